// Round 3
// baseline (749.510 us; speedup 1.0000x reference)
//
#include <hip/hip_runtime.h>
#include <hip/hip_bf16.h>
#include <math.h>

// Problem constants
#define BB 256
#define TT 512
#define EE 128
#define HH 128
#define NC 4
#define MM (BB * TT)   // 131072 rows of the input GEMM

typedef __bf16 bf16x8 __attribute__((ext_vector_type(8)));
typedef __bf16 bf16x4 __attribute__((ext_vector_type(4)));
typedef float  f32x4  __attribute__((ext_vector_type(4)));
typedef float  f32x2  __attribute__((ext_vector_type(2)));

// Branch-free tanh: 1 - 2/(1+e^{2x}) with e^{2x} = exp2(2*log2e*x).
__device__ __forceinline__ float fast_tanh(float x) {
    float t = __builtin_amdgcn_exp2f(x * 2.885390081777927f);
    return 1.f - 2.f * __builtin_amdgcn_rcpf(1.f + t);
}

// Workgroup barrier that does NOT drain vmcnt (unlike __syncthreads, which
// emits s_waitcnt vmcnt(0) lgkmcnt(0) before s_barrier). LDS ordering needs
// only lgkmcnt(0); global prefetch loads stay in flight across steps.
__device__ __forceinline__ void lds_barrier() {
    asm volatile("s_waitcnt lgkmcnt(0)" ::: "memory");
    __builtin_amdgcn_s_barrier();
    asm volatile("" ::: "memory");
}

// ---------------------------------------------------------------------------
// Kernel 1: x_proj[m,h] = sum_e emb[x[m],e] * W_ih[h,e] + b_ih[h] + b_hh[h]
// Split-bf16 GEMM (AhWh + AlWh + AhWl). (unchanged this round)
// ---------------------------------------------------------------------------
template <typename XPT>
__global__ __launch_bounds__(256, 2) void embed_gemm(
    const int* __restrict__ x, const float* __restrict__ emb,
    const float* __restrict__ Wih, const float* __restrict__ bih,
    const float* __restrict__ bhh, XPT* __restrict__ xpout)
{
    const int tid = threadIdx.x;
    const int m0  = blockIdx.x * 128;

    const int LDA = 72;  // bf16 units per 64-wide half row (144 B, 16B-aligned)
    __shared__ __bf16 Ah[128 * 72];
    __shared__ __bf16 Al[128 * 72];
    __shared__ __bf16 Wh[128 * 72];
    __shared__ __bf16 Wl[128 * 72];
    __shared__ float  bias_s[128];
    __shared__ int    gix[128];

    if (tid < 128) {
        gix[tid]    = x[m0 + tid];
        bias_s[tid] = bih[tid] + bhh[tid];
    }

    const int lane = tid & 63, wid = tid >> 6;
    const int col  = lane & 15, quad = lane >> 4;

    f32x4 acc[2][8];
#pragma unroll
    for (int mt = 0; mt < 2; ++mt)
#pragma unroll
        for (int nt = 0; nt < 8; ++nt) acc[mt][nt] = f32x4{0.f, 0.f, 0.f, 0.f};

    __syncthreads();   // gix/bias visible

#pragma unroll
    for (int half = 0; half < 2; ++half) {
        // Stage this K-half: 2048 float4 chunks each for A and W.
#pragma unroll
        for (int it = 0; it < 8; ++it) {
            int c   = it * 256 + tid;   // 0..2047
            int row = c >> 4;           // 0..127
            int seg = c & 15;           // float4 within the 64-col half

            float4 wv = ((const float4*)Wih)[row * 32 + half * 16 + seg];
            bf16x4 wh, wl;
            wh[0] = (__bf16)wv.x; wl[0] = (__bf16)(wv.x - (float)wh[0]);
            wh[1] = (__bf16)wv.y; wl[1] = (__bf16)(wv.y - (float)wh[1]);
            wh[2] = (__bf16)wv.z; wl[2] = (__bf16)(wv.z - (float)wh[2]);
            wh[3] = (__bf16)wv.w; wl[3] = (__bf16)(wv.w - (float)wh[3]);
            *(bf16x4*)&Wh[row * LDA + seg * 4] = wh;
            *(bf16x4*)&Wl[row * LDA + seg * 4] = wl;

            int gi = gix[row];
            float4 av = ((const float4*)emb)[(size_t)gi * 32 + half * 16 + seg];
            bf16x4 ah, al;
            ah[0] = (__bf16)av.x; al[0] = (__bf16)(av.x - (float)ah[0]);
            ah[1] = (__bf16)av.y; al[1] = (__bf16)(av.y - (float)ah[1]);
            ah[2] = (__bf16)av.z; al[2] = (__bf16)(av.z - (float)ah[2]);
            ah[3] = (__bf16)av.w; al[3] = (__bf16)(av.w - (float)ah[3]);
            *(bf16x4*)&Ah[row * LDA + seg * 4] = ah;
            *(bf16x4*)&Al[row * LDA + seg * 4] = al;
        }
        __syncthreads();   // staged data visible

#pragma unroll
        for (int kk = 0; kk < 2; ++kk) {  // K steps of 32 within the half
            bf16x8 afh[2], afl[2];
#pragma unroll
            for (int mt = 0; mt < 2; ++mt) {
                int ro = (wid * 32 + mt * 16 + col) * LDA + kk * 32 + quad * 8;
                afh[mt] = *(const bf16x8*)&Ah[ro];
                afl[mt] = *(const bf16x8*)&Al[ro];
            }
#pragma unroll
            for (int nt = 0; nt < 8; ++nt) {
                int ro = (nt * 16 + col) * LDA + kk * 32 + quad * 8;
                bf16x8 wfh = *(const bf16x8*)&Wh[ro];
                bf16x8 wfl = *(const bf16x8*)&Wl[ro];
#pragma unroll
                for (int mt = 0; mt < 2; ++mt) {
                    acc[mt][nt] = __builtin_amdgcn_mfma_f32_16x16x32_bf16(afh[mt], wfh, acc[mt][nt], 0, 0, 0);
                    acc[mt][nt] = __builtin_amdgcn_mfma_f32_16x16x32_bf16(afl[mt], wfh, acc[mt][nt], 0, 0, 0);
                    acc[mt][nt] = __builtin_amdgcn_mfma_f32_16x16x32_bf16(afh[mt], wfl, acc[mt][nt], 0, 0, 0);
                }
            }
        }
        if (half == 0) __syncthreads();   // MFMA reads done before restage
    }

    // Epilogue: C/D layout col=lane&15, row=(lane>>4)*4+reg  [verified m89/m91]
#pragma unroll
    for (int mt = 0; mt < 2; ++mt) {
#pragma unroll
        for (int nt = 0; nt < 8; ++nt) {
            int m = m0 + wid * 32 + mt * 16 + quad * 4;
            int n = nt * 16 + col;
            float bs = bias_s[n];
#pragma unroll
            for (int r = 0; r < 4; ++r)
                xpout[(size_t)(m + r) * 128 + n] = (XPT)(acc[mt][nt][r] + bs);
        }
    }
}

// ---------------------------------------------------------------------------
// Kernel 2: sequential scan  h = tanh(x_proj[t] + W_hh @ h)   (512 steps)
// Round 7: rounds 5/6 proved the step is LATENCY-bound, not structure-bound:
// 848 cy/step with only ~195 cy of VALU issue (VALUBusy 23%) and 1 wave/SIMD
// -> ~650 cy of unhidden ds_read/shfl/barrier latency per step. Fix: put
// FOUR independent batch scans in one block (grid 64). W_hh VGPRs are shared
// across all 4 (zero extra weight cost); the 4 batches' compute interleaves
// so each batch's latency is hidden under the others' issue, and ONE barrier
// serves all 4 batches' step boundary. Expected: issue-bound ~200cy/step.
// Per-batch structure unchanged: wave w owns outputs [32w,32w+32), lane =
// kh*32+o computes output 32w+o over K-half [64kh,64kh+64); __shfl_xor(32)
// K-reduce; per-batch double-buffered h_s, static buffer index (ts&1).
// ---------------------------------------------------------------------------
#define BPB 4   // batches per block
template <typename XPT>
__global__ __launch_bounds__(256, 1) void rnn_scan(
    const XPT* __restrict__ xp, const float* __restrict__ Whh,
    const float* __restrict__ h0, float* __restrict__ hlast)
{
    const int b0   = blockIdx.x * BPB;
    const int tid  = threadIdx.x;
    const int w    = tid >> 6;       // wave id: owns outputs [32w, 32w+32)
    const int lane = tid & 63;
    const int o    = lane & 31;      // output index within wave's slice
    const int kh   = lane >> 5;      // K-half: [64kh, 64kh+64)

    __shared__ float h_s[BPB][2][128];   // per-batch double buffer

    // Weights: row (32w+o), K-slice [64kh, 64kh+64) as 16 float4 (64 VGPRs).
    // SHARED by all BPB batches.
    f32x4 wv[16];
    {
        const float* r = Whh + (size_t)(w * 32 + o) * 128 + kh * 64;
#pragma unroll
        for (int c = 0; c < 16; ++c) wv[c] = *(const f32x4*)(r + c * 4);
    }
    // Pin: asm result cannot be rematerialized -> weights stay in VGPRs.
#pragma unroll
    for (int c = 0; c < 16; ++c) asm volatile("" : "+v"(wv[c]));

    if (tid < 128) {
#pragma unroll
        for (int bt = 0; bt < BPB; ++bt)
            h_s[bt][0][tid] = h0[(b0 + bt) * 128 + tid];
    }

    // x_proj register rings: 8 steps ahead, per batch.
    const int xoff = w * 32 + o;
    float xv[BPB][8];
#pragma unroll
    for (int bt = 0; bt < BPB; ++bt)
#pragma unroll
        for (int s = 0; s < 8; ++s)
            xv[bt][s] = (float)xp[((size_t)(b0 + bt) * TT + s) * 128 + xoff];
    lds_barrier();

    for (int tw = 0; tw < TT; tw += 8) {
#pragma unroll
        for (int ts = 0; ts < 8; ++ts) {
            const int c = ts & 1;    // static double-buffer index
#pragma unroll
            for (int bt = 0; bt < BPB; ++bt) {
                // broadcast read of this lane's K-half of h (uniform per
                // half-wave -> 2-way aliasing = conflict-free)
                const float* hq = &h_s[bt][c][kh * 64];
                f32x4 h4[16];
#pragma unroll
                for (int u = 0; u < 16; ++u) h4[u] = *(const f32x4*)&hq[u * 4];

                f32x4 aA = f32x4{0.f, 0.f, 0.f, 0.f};
                f32x4 aB = f32x4{0.f, 0.f, 0.f, 0.f};
#pragma unroll
                for (int u = 0; u < 8; ++u) {
                    aA += wv[u]     * h4[u];
                    aB += wv[u + 8] * h4[u + 8];
                }
                f32x4 at = aA + aB;
                float p  = (at[0] + at[1]) + (at[2] + at[3]);
                // K-reduce across the two halves: one cross-lane op, no LDS.
                p += __shfl_xor(p, 32, 64);
                float hnew = fast_tanh(p + xv[bt][ts]);

                if (lane < 32) h_s[bt][c ^ 1][w * 32 + o] = hnew;
                // refill ring slot for step tw+8+ts; stays in flight across
                // the raw barriers (no vmcnt drain).
                if (tw + 8 < TT)
                    xv[bt][ts] = (float)xp[((size_t)(b0 + bt) * TT + tw + 8 + ts) * 128 + xoff];
            }
            lds_barrier();   // ONE barrier serves all BPB batches' step
        }
    }
    if (tid < 128) {
#pragma unroll
        for (int bt = 0; bt < BPB; ++bt)
            hlast[(b0 + bt) * 128 + tid] = h_s[bt][0][tid];
    }
}

// ---------------------------------------------------------------------------
// Kernel 3: MLP head. hidden = relu(h @ W1^T + b1) [256]; logits = hidden @ W2^T + b2 [4]
// One block per batch row. Also writes last_hidden to d_out. (unchanged)
// ---------------------------------------------------------------------------
__global__ __launch_bounds__(256, 2) void mlp_head(
    const float* __restrict__ hlast, const float* __restrict__ W1,
    const float* __restrict__ b1, const float* __restrict__ W2,
    const float* __restrict__ b2, float* __restrict__ out)
{
    const int b = blockIdx.x, tid = threadIdx.x;
    __shared__ float h_row[128];
    __shared__ float hid[256];

    if (tid < 128) {
        float hv = hlast[b * 128 + tid];
        h_row[tid] = hv;
        out[1024 + b * 128 + tid] = hv;   // last_hidden output (fp32)
    }
    __syncthreads();

    // hidden[tid] = relu(b1[tid] + sum_k W1[tid][k] * h[k]); W1 from L2
    {
        float acc = b1[tid];
        const float4* wrow = (const float4*)(W1 + (size_t)tid * 128);
#pragma unroll
        for (int k4 = 0; k4 < 32; ++k4) {
            float4 wv = wrow[k4];
            acc += wv.x * h_row[k4 * 4 + 0] + wv.y * h_row[k4 * 4 + 1]
                 + wv.z * h_row[k4 * 4 + 2] + wv.w * h_row[k4 * 4 + 3];
        }
        hid[tid] = fmaxf(acc, 0.f);
    }
    __syncthreads();

    // logits: wave w -> class w; 64-lane strided partials + shuffle reduce
    const int wv = tid >> 6, lane = tid & 63;
    float s = 0.f;
#pragma unroll
    for (int qq = 0; qq < 4; ++qq)
        s += hid[qq * 64 + lane] * W2[wv * 256 + qq * 64 + lane];
#pragma unroll
    for (int off = 32; off > 0; off >>= 1) s += __shfl_down(s, off);
    if (lane == 0) out[b * 4 + wv] = s + b2[wv];
}

// ---------------------------------------------------------------------------
extern "C" void kernel_launch(void* const* d_in, const int* in_sizes, int n_in,
                              void* d_out, int out_size, void* d_ws, size_t ws_size,
                              hipStream_t stream)
{
    const int*   x   = (const int*)d_in[0];
    const float* h0  = (const float*)d_in[1];
    const float* emb = (const float*)d_in[2];
    const float* Wih = (const float*)d_in[3];
    const float* Whh = (const float*)d_in[4];
    const float* bih = (const float*)d_in[5];
    const float* bhh = (const float*)d_in[6];
    const float* W1  = (const float*)d_in[7];
    const float* b1  = (const float*)d_in[8];
    const float* W2  = (const float*)d_in[9];
    const float* b2  = (const float*)d_in[10];
    float* out = (float*)d_out;

    const size_t xp_f32_bytes = (size_t)MM * 128 * sizeof(float);   // 64 MB
    const size_t hl_bytes     = (size_t)BB * 128 * sizeof(float);   // 128 KB

    if (ws_size >= xp_f32_bytes + hl_bytes) {
        float* xpw = (float*)d_ws;
        float* hl  = (float*)((char*)d_ws + xp_f32_bytes);
        embed_gemm<float><<<MM / 128, 256, 0, stream>>>(x, emb, Wih, bih, bhh, xpw);
        rnn_scan<float><<<BB / BPB, 256, 0, stream>>>(xpw, Whh, h0, hl);
        mlp_head<<<BB, 256, 0, stream>>>(hl, W1, b1, W2, b2, out);
    } else {
        // Fallback: bf16 x_proj storage (32 MB) if workspace is small
        __bf16* xpw = (__bf16*)d_ws;
        float*  hl  = (float*)((char*)d_ws + (size_t)MM * 128 * sizeof(__bf16));
        embed_gemm<__bf16><<<MM / 128, 256, 0, stream>>>(x, emb, Wih, bih, bhh, xpw);
        rnn_scan<__bf16><<<BB / BPB, 256, 0, stream>>>(xpw, Whh, h0, hl);
        mlp_head<<<BB, 256, 0, stream>>>(hl, W1, b1, W2, b2, out);
    }
}

// Round 4
// 533.656 us; speedup vs baseline: 1.4045x; 1.4045x over previous
//
#include <hip/hip_runtime.h>
#include <hip/hip_bf16.h>
#include <math.h>

// Problem constants
#define BB 256
#define TT 512
#define EE 128
#define HH 128
#define NC 4
#define MM (BB * TT)   // 131072 rows of the input GEMM

typedef __bf16 bf16x8 __attribute__((ext_vector_type(8)));
typedef __bf16 bf16x4 __attribute__((ext_vector_type(4)));
typedef float  f32x4  __attribute__((ext_vector_type(4)));
typedef float  f32x2  __attribute__((ext_vector_type(2)));

// Branch-free tanh: 1 - 2/(1+e^{2x}) with e^{2x} = exp2(2*log2e*x).
__device__ __forceinline__ float fast_tanh(float x) {
    float t = __builtin_amdgcn_exp2f(x * 2.885390081777927f);
    return 1.f - 2.f * __builtin_amdgcn_rcpf(1.f + t);
}

// Workgroup barrier that does NOT drain vmcnt (unlike __syncthreads, which
// emits s_waitcnt vmcnt(0) lgkmcnt(0) before s_barrier). LDS ordering needs
// only lgkmcnt(0); global prefetch loads stay in flight across steps.
__device__ __forceinline__ void lds_barrier() {
    asm volatile("s_waitcnt lgkmcnt(0)" ::: "memory");
    __builtin_amdgcn_s_barrier();
    asm volatile("" ::: "memory");
}

// ---------------------------------------------------------------------------
// Kernel 1: x_proj[m,h] = sum_e emb[x[m],e] * W_ih[h,e] + b_ih[h] + b_hh[h]
// Split-bf16 GEMM (AhWh + AlWh + AhWl). (unchanged this round)
// ---------------------------------------------------------------------------
template <typename XPT>
__global__ __launch_bounds__(256, 2) void embed_gemm(
    const int* __restrict__ x, const float* __restrict__ emb,
    const float* __restrict__ Wih, const float* __restrict__ bih,
    const float* __restrict__ bhh, XPT* __restrict__ xpout)
{
    const int tid = threadIdx.x;
    const int m0  = blockIdx.x * 128;

    const int LDA = 72;  // bf16 units per 64-wide half row (144 B, 16B-aligned)
    __shared__ __bf16 Ah[128 * 72];
    __shared__ __bf16 Al[128 * 72];
    __shared__ __bf16 Wh[128 * 72];
    __shared__ __bf16 Wl[128 * 72];
    __shared__ float  bias_s[128];
    __shared__ int    gix[128];

    if (tid < 128) {
        gix[tid]    = x[m0 + tid];
        bias_s[tid] = bih[tid] + bhh[tid];
    }

    const int lane = tid & 63, wid = tid >> 6;
    const int col  = lane & 15, quad = lane >> 4;

    f32x4 acc[2][8];
#pragma unroll
    for (int mt = 0; mt < 2; ++mt)
#pragma unroll
        for (int nt = 0; nt < 8; ++nt) acc[mt][nt] = f32x4{0.f, 0.f, 0.f, 0.f};

    __syncthreads();   // gix/bias visible

#pragma unroll
    for (int half = 0; half < 2; ++half) {
        // Stage this K-half: 2048 float4 chunks each for A and W.
#pragma unroll
        for (int it = 0; it < 8; ++it) {
            int c   = it * 256 + tid;   // 0..2047
            int row = c >> 4;           // 0..127
            int seg = c & 15;           // float4 within the 64-col half

            float4 wv = ((const float4*)Wih)[row * 32 + half * 16 + seg];
            bf16x4 wh, wl;
            wh[0] = (__bf16)wv.x; wl[0] = (__bf16)(wv.x - (float)wh[0]);
            wh[1] = (__bf16)wv.y; wl[1] = (__bf16)(wv.y - (float)wh[1]);
            wh[2] = (__bf16)wv.z; wl[2] = (__bf16)(wv.z - (float)wh[2]);
            wh[3] = (__bf16)wv.w; wl[3] = (__bf16)(wv.w - (float)wh[3]);
            *(bf16x4*)&Wh[row * LDA + seg * 4] = wh;
            *(bf16x4*)&Wl[row * LDA + seg * 4] = wl;

            int gi = gix[row];
            float4 av = ((const float4*)emb)[(size_t)gi * 32 + half * 16 + seg];
            bf16x4 ah, al;
            ah[0] = (__bf16)av.x; al[0] = (__bf16)(av.x - (float)ah[0]);
            ah[1] = (__bf16)av.y; al[1] = (__bf16)(av.y - (float)ah[1]);
            ah[2] = (__bf16)av.z; al[2] = (__bf16)(av.z - (float)ah[2]);
            ah[3] = (__bf16)av.w; al[3] = (__bf16)(av.w - (float)ah[3]);
            *(bf16x4*)&Ah[row * LDA + seg * 4] = ah;
            *(bf16x4*)&Al[row * LDA + seg * 4] = al;
        }
        __syncthreads();   // staged data visible

#pragma unroll
        for (int kk = 0; kk < 2; ++kk) {  // K steps of 32 within the half
            bf16x8 afh[2], afl[2];
#pragma unroll
            for (int mt = 0; mt < 2; ++mt) {
                int ro = (wid * 32 + mt * 16 + col) * LDA + kk * 32 + quad * 8;
                afh[mt] = *(const bf16x8*)&Ah[ro];
                afl[mt] = *(const bf16x8*)&Al[ro];
            }
#pragma unroll
            for (int nt = 0; nt < 8; ++nt) {
                int ro = (nt * 16 + col) * LDA + kk * 32 + quad * 8;
                bf16x8 wfh = *(const bf16x8*)&Wh[ro];
                bf16x8 wfl = *(const bf16x8*)&Wl[ro];
#pragma unroll
                for (int mt = 0; mt < 2; ++mt) {
                    acc[mt][nt] = __builtin_amdgcn_mfma_f32_16x16x32_bf16(afh[mt], wfh, acc[mt][nt], 0, 0, 0);
                    acc[mt][nt] = __builtin_amdgcn_mfma_f32_16x16x32_bf16(afl[mt], wfh, acc[mt][nt], 0, 0, 0);
                    acc[mt][nt] = __builtin_amdgcn_mfma_f32_16x16x32_bf16(afh[mt], wfl, acc[mt][nt], 0, 0, 0);
                }
            }
        }
        if (half == 0) __syncthreads();   // MFMA reads done before restage
    }

    // Epilogue: C/D layout col=lane&15, row=(lane>>4)*4+reg  [verified m89/m91]
#pragma unroll
    for (int mt = 0; mt < 2; ++mt) {
#pragma unroll
        for (int nt = 0; nt < 8; ++nt) {
            int m = m0 + wid * 32 + mt * 16 + quad * 4;
            int n = nt * 16 + col;
            float bs = bias_s[n];
#pragma unroll
            for (int r = 0; r < 4; ++r)
                xpout[(size_t)(m + r) * 128 + n] = (XPT)(acc[mt][nt][r] + bs);
        }
    }
}

// ---------------------------------------------------------------------------
// x_proj loader: f32x4 from either float or __bf16 storage
// ---------------------------------------------------------------------------
template <typename XPT>
__device__ __forceinline__ f32x4 load_xp4(const XPT* p) {
    if constexpr (sizeof(XPT) == 4) {
        return *(const f32x4*)p;
    } else {
        bf16x4 v = *(const bf16x4*)p;
        return f32x4{(float)v[0], (float)v[1], (float)v[2], (float)v[3]};
    }
}

// ---------------------------------------------------------------------------
// Kernel 2: sequential scan  h = tanh(x_proj[t] + W_hh @ h)   (512 steps)
// Round 8: rounds 4/6/7 all land at ~12 cy per wave-level DS instruction
// (58->795cy, 68->848cy, 260->3000cy): the scan is LDS-PIPE-THROUGHPUT
// bound (one DS pipe/CU). Scalar broadcast needs 64 ds_read_b128/CU/step
// no matter the wave split. Escape = MFMA: hardware shares operands across
// lanes internally. Batch 16 rows (M=16) per block -> per step per wave:
// 8 ds_read_b128 (H frags, hi/lo x 4 k-tiles, SHARED across the wave's 4
// hid-tiles) + 8 ds_write_b64. 2 waves/block: ~32 DS/CU/step (~250cy) +
// 48 MFMA/wave (~240cy, per-SIMD pipe, overlaps DS).
// Swapped operands mfma(A=W_frag, B=H_frag) -> C[m=hid][n=batch]: each lane
// holds 4 CONSECUTIVE hids for one batch = contiguous 8B LDS write-back
// (no transpose). Fragment layouts identical to embed_gemm's (verified).
// 3-term hi/lo split keeps f32 accuracy (dropped lo*lo ~ 2^-18).
// H swizzle: elem = b*128 + (h ^ ((b&7)<<3)) — bank-minimal reads+writes.
// ---------------------------------------------------------------------------
#define SB 16   // batches per scan block
template <typename XPT>
__global__ __launch_bounds__(128, 1) void rnn_scan(
    const XPT* __restrict__ xp, const float* __restrict__ Whh,
    const float* __restrict__ h0, float* __restrict__ hlast)
{
    const int tid  = threadIdx.x;
    const int w    = tid >> 6;       // wave id: owns hid rows [64w, 64w+64)
    const int l    = tid & 63;
    const int col  = l & 15;         // batch (B-frag row / C col)
    const int quad = l >> 4;         // k-subtile / C row group
    const int bg   = blockIdx.x * SB;

    __shared__ __bf16 Hh[2][SB * 128];   // hi plane, double-buffered
    __shared__ __bf16 Hl[2][SB * 128];   // lo plane

    // Resident W_hh fragments: A-layout A[m=hid row][k], lane holds
    // row (base + (l&15)), k = kt*32 + (l>>4)*8 + j  (same as embed_gemm).
    bf16x8 Wf_h[4][4], Wf_l[4][4];
#pragma unroll
    for (int ht = 0; ht < 4; ++ht)
#pragma unroll
        for (int kt = 0; kt < 4; ++kt) {
            const float* src = Whh + (size_t)(w * 64 + ht * 16 + col) * 128
                             + kt * 32 + quad * 8;
            float4 a = *(const float4*)(src);
            float4 b = *(const float4*)(src + 4);
            float v[8] = {a.x, a.y, a.z, a.w, b.x, b.y, b.z, b.w};
            bf16x8 hi, lo;
#pragma unroll
            for (int j = 0; j < 8; ++j) {
                hi[j] = (__bf16)v[j];
                lo[j] = (__bf16)(v[j] - (float)hi[j]);
            }
            Wf_h[ht][kt] = hi; Wf_l[ht][kt] = lo;
        }
    // Pin: keep all 32 fragments resident in VGPRs (no spill/remat).
#pragma unroll
    for (int ht = 0; ht < 4; ++ht)
#pragma unroll
        for (int kt = 0; kt < 4; ++kt)
            asm volatile("" : "+v"(Wf_h[ht][kt]), "+v"(Wf_l[ht][kt]));

    // Stage h0 into buffer 0 (swizzled, hi/lo split).
#pragma unroll
    for (int i = 0; i < SB * 128; i += 128) {
        int idx = i + tid, b = idx >> 7, h = idx & 127;
        float v = h0[(bg + b) * 128 + h];
        __bf16 hi = (__bf16)v;
        int e = b * 128 + (h ^ ((b & 7) << 3));
        Hh[0][e] = hi;
        Hl[0][e] = (__bf16)(v - (float)hi);
    }

    // x_proj prefetch ring, 2 steps deep. Lane covers batch=bg+col,
    // hids [w*64+ht*16+quad*4 .. +4) per tile -> one dwordx4 per tile.
    const XPT* xpb = xp + (size_t)(bg + col) * TT * 128 + w * 64 + quad * 4;
    f32x4 xv[2][4];
#pragma unroll
    for (int s = 0; s < 2; ++s)
#pragma unroll
        for (int ht = 0; ht < 4; ++ht)
            xv[s][ht] = load_xp4(xpb + (size_t)s * 128 + ht * 16);

    lds_barrier();

#define SCAN_STEP(t, par)                                                     \
    {                                                                         \
        bf16x8 Hf_h[4], Hf_l[4];                                              \
        _Pragma("unroll")                                                     \
        for (int kt = 0; kt < 4; ++kt) {                                      \
            int e = col * 128 + ((kt * 32 + quad * 8) ^ ((col & 7) << 3));    \
            Hf_h[kt] = *(const bf16x8*)&Hh[par][e];                           \
            Hf_l[kt] = *(const bf16x8*)&Hl[par][e];                           \
        }                                                                     \
        size_t roff = (size_t)((t) + 2 < TT ? (t) + 2 : TT - 1) * 128;        \
        f32x4 acc[4];                                                         \
        _Pragma("unroll")                                                     \
        for (int ht = 0; ht < 4; ++ht) acc[ht] = f32x4{0.f, 0.f, 0.f, 0.f};   \
        _Pragma("unroll")                                                     \
        for (int kt = 0; kt < 4; ++kt) {                                      \
            _Pragma("unroll")                                                 \
            for (int ht = 0; ht < 4; ++ht) {                                  \
                acc[ht] = __builtin_amdgcn_mfma_f32_16x16x32_bf16(            \
                    Wf_h[ht][kt], Hf_h[kt], acc[ht], 0, 0, 0);                \
                acc[ht] = __builtin_amdgcn_mfma_f32_16x16x32_bf16(            \
                    Wf_l[ht][kt], Hf_h[kt], acc[ht], 0, 0, 0);                \
                acc[ht] = __builtin_amdgcn_mfma_f32_16x16x32_bf16(            \
                    Wf_h[ht][kt], Hf_l[kt], acc[ht], 0, 0, 0);                \
            }                                                                 \
        }                                                                     \
        _Pragma("unroll")                                                     \
        for (int ht = 0; ht < 4; ++ht) {                                      \
            bf16x4 hh, hl;                                                    \
            _Pragma("unroll")                                                 \
            for (int r = 0; r < 4; ++r) {                                     \
                float hn = fast_tanh(acc[ht][r] + xv[par][ht][r]);            \
                hh[r] = (__bf16)hn;                                           \
                hl[r] = (__bf16)(hn - (float)hh[r]);                          \
            }                                                                 \
            xv[par][ht] = load_xp4(xpb + roff + ht * 16);                     \
            int hb = w * 64 + ht * 16 + quad * 4;                             \
            int e  = col * 128 + (hb ^ ((col & 7) << 3));                     \
            *(bf16x4*)&Hh[(par) ^ 1][e] = hh;                                 \
            *(bf16x4*)&Hl[(par) ^ 1][e] = hl;                                 \
        }                                                                     \
        lds_barrier();                                                        \
    }

    for (int t = 0; t < TT; t += 2) {
        SCAN_STEP(t, 0)
        SCAN_STEP(t + 1, 1)
    }
#undef SCAN_STEP

    // Final H is in buffer 0 (step 511 writes 1^1 = 0). Reconstruct f32.
#pragma unroll
    for (int i = 0; i < SB * 128; i += 128) {
        int idx = i + tid, b = idx >> 7, h = idx & 127;
        int e = b * 128 + (h ^ ((b & 7) << 3));
        hlast[(bg + b) * 128 + h] = (float)Hh[0][e] + (float)Hl[0][e];
    }
}

// ---------------------------------------------------------------------------
// Kernel 3: MLP head. hidden = relu(h @ W1^T + b1) [256]; logits = hidden @ W2^T + b2 [4]
// One block per batch row. Also writes last_hidden to d_out. (unchanged)
// ---------------------------------------------------------------------------
__global__ __launch_bounds__(256, 2) void mlp_head(
    const float* __restrict__ hlast, const float* __restrict__ W1,
    const float* __restrict__ b1, const float* __restrict__ W2,
    const float* __restrict__ b2, float* __restrict__ out)
{
    const int b = blockIdx.x, tid = threadIdx.x;
    __shared__ float h_row[128];
    __shared__ float hid[256];

    if (tid < 128) {
        float hv = hlast[b * 128 + tid];
        h_row[tid] = hv;
        out[1024 + b * 128 + tid] = hv;   // last_hidden output (fp32)
    }
    __syncthreads();

    // hidden[tid] = relu(b1[tid] + sum_k W1[tid][k] * h[k]); W1 from L2
    {
        float acc = b1[tid];
        const float4* wrow = (const float4*)(W1 + (size_t)tid * 128);
#pragma unroll
        for (int k4 = 0; k4 < 32; ++k4) {
            float4 wv = wrow[k4];
            acc += wv.x * h_row[k4 * 4 + 0] + wv.y * h_row[k4 * 4 + 1]
                 + wv.z * h_row[k4 * 4 + 2] + wv.w * h_row[k4 * 4 + 3];
        }
        hid[tid] = fmaxf(acc, 0.f);
    }
    __syncthreads();

    // logits: wave w -> class w; 64-lane strided partials + shuffle reduce
    const int wv = tid >> 6, lane = tid & 63;
    float s = 0.f;
#pragma unroll
    for (int qq = 0; qq < 4; ++qq)
        s += hid[qq * 64 + lane] * W2[wv * 256 + qq * 64 + lane];
#pragma unroll
    for (int off = 32; off > 0; off >>= 1) s += __shfl_down(s, off);
    if (lane == 0) out[b * 4 + wv] = s + b2[wv];
}

// ---------------------------------------------------------------------------
extern "C" void kernel_launch(void* const* d_in, const int* in_sizes, int n_in,
                              void* d_out, int out_size, void* d_ws, size_t ws_size,
                              hipStream_t stream)
{
    const int*   x   = (const int*)d_in[0];
    const float* h0  = (const float*)d_in[1];
    const float* emb = (const float*)d_in[2];
    const float* Wih = (const float*)d_in[3];
    const float* Whh = (const float*)d_in[4];
    const float* bih = (const float*)d_in[5];
    const float* bhh = (const float*)d_in[6];
    const float* W1  = (const float*)d_in[7];
    const float* b1  = (const float*)d_in[8];
    const float* W2  = (const float*)d_in[9];
    const float* b2  = (const float*)d_in[10];
    float* out = (float*)d_out;

    const size_t xp_f32_bytes = (size_t)MM * 128 * sizeof(float);   // 64 MB
    const size_t hl_bytes     = (size_t)BB * 128 * sizeof(float);   // 128 KB

    if (ws_size >= xp_f32_bytes + hl_bytes) {
        float* xpw = (float*)d_ws;
        float* hl  = (float*)((char*)d_ws + xp_f32_bytes);
        embed_gemm<float><<<MM / 128, 256, 0, stream>>>(x, emb, Wih, bih, bhh, xpw);
        rnn_scan<float><<<BB / SB, 128, 0, stream>>>(xpw, Whh, h0, hl);
        mlp_head<<<BB, 256, 0, stream>>>(hl, W1, b1, W2, b2, out);
    } else {
        // Fallback: bf16 x_proj storage (32 MB) if workspace is small
        __bf16* xpw = (__bf16*)d_ws;
        float*  hl  = (float*)((char*)d_ws + (size_t)MM * 128 * sizeof(__bf16));
        embed_gemm<__bf16><<<MM / 128, 256, 0, stream>>>(x, emb, Wih, bih, bhh, xpw);
        rnn_scan<__bf16><<<BB / SB, 128, 0, stream>>>(xpw, Whh, h0, hl);
        mlp_head<<<BB, 256, 0, stream>>>(hl, W1, b1, W2, b2, out);
    }
}

// Round 5
// 279.256 us; speedup vs baseline: 2.6839x; 1.9110x over previous
//
#include <hip/hip_runtime.h>
#include <hip/hip_bf16.h>
#include <math.h>

// Problem constants
#define BB 256
#define TT 512
#define EE 128
#define HH 128
#define NC 4
#define MM (BB * TT)   // 131072 rows of the input GEMM

typedef __bf16 bf16x8 __attribute__((ext_vector_type(8)));
typedef __bf16 bf16x4 __attribute__((ext_vector_type(4)));
typedef float  f32x4  __attribute__((ext_vector_type(4)));
typedef float  f32x2  __attribute__((ext_vector_type(2)));

// Branch-free tanh: 1 - 2/(1+e^{2x}) with e^{2x} = exp2(2*log2e*x).
__device__ __forceinline__ float fast_tanh(float x) {
    float t = __builtin_amdgcn_exp2f(x * 2.885390081777927f);
    return 1.f - 2.f * __builtin_amdgcn_rcpf(1.f + t);
}

// Workgroup barrier that does NOT drain vmcnt (unlike __syncthreads, which
// emits s_waitcnt vmcnt(0) lgkmcnt(0) before s_barrier). LDS ordering needs
// only lgkmcnt(0); global prefetch loads stay in flight across steps.
__device__ __forceinline__ void lds_barrier() {
    asm volatile("s_waitcnt lgkmcnt(0)" ::: "memory");
    __builtin_amdgcn_s_barrier();
    asm volatile("" ::: "memory");
}

// Cross-lane sum with the xor-16 / xor-32 partner via gfx950's
// v_permlane{16,32}_swap (VALU pipe, ~4cy) instead of ds_bpermute
// (DS pipe, ~120cy latency). With both inputs = p, the two outputs are
// {p[self], p[partner]} in some order on every lane, so t1+t2 is the
// pair-sum regardless of the swap's row-direction convention.
__device__ __forceinline__ float xor16_sum(float p) {
    float t1 = p, t2 = p;
    asm volatile("v_permlane16_swap_b32 %0, %1" : "+v"(t1), "+v"(t2));
    return t1 + t2;
}
__device__ __forceinline__ float xor32_sum(float p) {
    float t1 = p, t2 = p;
    asm volatile("v_permlane32_swap_b32 %0, %1" : "+v"(t1), "+v"(t2));
    return t1 + t2;
}

// ---------------------------------------------------------------------------
// Kernel 1: x_proj[m,h] = sum_e emb[x[m],e] * W_ih[h,e] + b_ih[h] + b_hh[h]
// Split-bf16 GEMM (AhWh + AlWh + AhWl). (unchanged this round)
// ---------------------------------------------------------------------------
template <typename XPT>
__global__ __launch_bounds__(256, 2) void embed_gemm(
    const int* __restrict__ x, const float* __restrict__ emb,
    const float* __restrict__ Wih, const float* __restrict__ bih,
    const float* __restrict__ bhh, XPT* __restrict__ xpout)
{
    const int tid = threadIdx.x;
    const int m0  = blockIdx.x * 128;

    const int LDA = 72;  // bf16 units per 64-wide half row (144 B, 16B-aligned)
    __shared__ __bf16 Ah[128 * 72];
    __shared__ __bf16 Al[128 * 72];
    __shared__ __bf16 Wh[128 * 72];
    __shared__ __bf16 Wl[128 * 72];
    __shared__ float  bias_s[128];
    __shared__ int    gix[128];

    if (tid < 128) {
        gix[tid]    = x[m0 + tid];
        bias_s[tid] = bih[tid] + bhh[tid];
    }

    const int lane = tid & 63, wid = tid >> 6;
    const int col  = lane & 15, quad = lane >> 4;

    f32x4 acc[2][8];
#pragma unroll
    for (int mt = 0; mt < 2; ++mt)
#pragma unroll
        for (int nt = 0; nt < 8; ++nt) acc[mt][nt] = f32x4{0.f, 0.f, 0.f, 0.f};

    __syncthreads();   // gix/bias visible

#pragma unroll
    for (int half = 0; half < 2; ++half) {
        // Stage this K-half: 2048 float4 chunks each for A and W.
#pragma unroll
        for (int it = 0; it < 8; ++it) {
            int c   = it * 256 + tid;   // 0..2047
            int row = c >> 4;           // 0..127
            int seg = c & 15;           // float4 within the 64-col half

            float4 wv = ((const float4*)Wih)[row * 32 + half * 16 + seg];
            bf16x4 wh, wl;
            wh[0] = (__bf16)wv.x; wl[0] = (__bf16)(wv.x - (float)wh[0]);
            wh[1] = (__bf16)wv.y; wl[1] = (__bf16)(wv.y - (float)wh[1]);
            wh[2] = (__bf16)wv.z; wl[2] = (__bf16)(wv.z - (float)wh[2]);
            wh[3] = (__bf16)wv.w; wl[3] = (__bf16)(wv.w - (float)wh[3]);
            *(bf16x4*)&Wh[row * LDA + seg * 4] = wh;
            *(bf16x4*)&Wl[row * LDA + seg * 4] = wl;

            int gi = gix[row];
            float4 av = ((const float4*)emb)[(size_t)gi * 32 + half * 16 + seg];
            bf16x4 ah, al;
            ah[0] = (__bf16)av.x; al[0] = (__bf16)(av.x - (float)ah[0]);
            ah[1] = (__bf16)av.y; al[1] = (__bf16)(av.y - (float)ah[1]);
            ah[2] = (__bf16)av.z; al[2] = (__bf16)(av.z - (float)ah[2]);
            ah[3] = (__bf16)av.w; al[3] = (__bf16)(av.w - (float)ah[3]);
            *(bf16x4*)&Ah[row * LDA + seg * 4] = ah;
            *(bf16x4*)&Al[row * LDA + seg * 4] = al;
        }
        __syncthreads();   // staged data visible

#pragma unroll
        for (int kk = 0; kk < 2; ++kk) {  // K steps of 32 within the half
            bf16x8 afh[2], afl[2];
#pragma unroll
            for (int mt = 0; mt < 2; ++mt) {
                int ro = (wid * 32 + mt * 16 + col) * LDA + kk * 32 + quad * 8;
                afh[mt] = *(const bf16x8*)&Ah[ro];
                afl[mt] = *(const bf16x8*)&Al[ro];
            }
#pragma unroll
            for (int nt = 0; nt < 8; ++nt) {
                int ro = (nt * 16 + col) * LDA + kk * 32 + quad * 8;
                bf16x8 wfh = *(const bf16x8*)&Wh[ro];
                bf16x8 wfl = *(const bf16x8*)&Wl[ro];
#pragma unroll
                for (int mt = 0; mt < 2; ++mt) {
                    acc[mt][nt] = __builtin_amdgcn_mfma_f32_16x16x32_bf16(afh[mt], wfh, acc[mt][nt], 0, 0, 0);
                    acc[mt][nt] = __builtin_amdgcn_mfma_f32_16x16x32_bf16(afl[mt], wfh, acc[mt][nt], 0, 0, 0);
                    acc[mt][nt] = __builtin_amdgcn_mfma_f32_16x16x32_bf16(afh[mt], wfl, acc[mt][nt], 0, 0, 0);
                }
            }
        }
        if (half == 0) __syncthreads();   // MFMA reads done before restage
    }

    // Epilogue: C/D layout col=lane&15, row=(lane>>4)*4+reg  [verified m89/m91]
#pragma unroll
    for (int mt = 0; mt < 2; ++mt) {
#pragma unroll
        for (int nt = 0; nt < 8; ++nt) {
            int m = m0 + wid * 32 + mt * 16 + quad * 4;
            int n = nt * 16 + col;
            float bs = bias_s[n];
#pragma unroll
            for (int r = 0; r < 4; ++r)
                xpout[(size_t)(m + r) * 128 + n] = (XPT)(acc[mt][nt][r] + bs);
        }
    }
}

// ---------------------------------------------------------------------------
// Kernel 2: sequential scan  h = tanh(x_proj[t] + W_hh @ h)   (512 steps)
// Round 9. Model (fits rounds 4/6/7/8): step time ~= DS instrs/CU/step x
// ~12cy (single shared DS pipe per CU). Round-6: 4 waves x (16 b128 reads +
// bpermute + write) ~= 816cy ~ 848 measured. This round halves the reads
// and moves the reduction off the DS pipe:
//  - 4-way K-split: lane (kq=l>>4, oo=l&15) computes outputs {32w+oo,
//    32w+16+oo} over K-quarter [32kq,32kq+32): 8 ds_read_b128/wave.
//  - kq-reduction via v_permlane{16,32}_swap (VALU pipe) - no ds_bpermute.
//  - bank swizzle: physical chunk uu=(u+kq)&7 rotation makes the 4 kq
//    groups' reads hit disjoint bank groups; folded into the WEIGHT load
//    order once at init, so step reads are base + imm offsets only.
// DS/CU/step: 4 x (8 reads + 2 writes) ~= 432cy -> predict ~600cy/step.
// Numerics identical to round-6 (f32 h, f32 W, same tanh).
// ---------------------------------------------------------------------------
template <typename XPT>
__global__ __launch_bounds__(256, 1) void rnn_scan(
    const XPT* __restrict__ xp, const float* __restrict__ Whh,
    const float* __restrict__ h0, float* __restrict__ hlast)
{
    const int b    = blockIdx.x;
    const int tid  = threadIdx.x;
    const int w    = tid >> 6;       // wave id: owns outputs [32w, 32w+32)
    const int lane = tid & 63;
    const int oo   = lane & 15;      // output column within wave's slice
    const int kq   = lane >> 4;      // K-quarter: [32kq, 32kq+32)

    const int A = w * 32 + oo;        // first output row
    const int Bo = A + 16;            // second output row

    __shared__ float h_s[2][128];     // double buffer, SWIZZLED layout

    // Physical layout of h index j: quarter q=j>>5 keeps its 32-f32 region,
    // but chunk u=(j>>2)&7 is stored at uu=(u+q)&7. Reads of quarter q chunk
    // uu then hit bank group uu*4 for every q simultaneously -> conflict-free.
    // Weights are loaded in PHYSICAL chunk order so the per-step inner loop
    // pairs wA[uu] with h4[uu] using compile-time indices only.
    f32x4 wA[8], wB[8];
#pragma unroll
    for (int uu = 0; uu < 8; ++uu) {
        int ul = (uu + 8 - kq) & 7;   // logical chunk stored at uu
        wA[uu] = *(const f32x4*)(Whh + (size_t)A  * 128 + kq * 32 + ul * 4);
        wB[uu] = *(const f32x4*)(Whh + (size_t)Bo * 128 + kq * 32 + ul * 4);
    }
    // Pin: asm result cannot be rematerialized -> weights stay in VGPRs.
#pragma unroll
    for (int c = 0; c < 8; ++c)
        asm volatile("" : "+v"(wA[c]), "+v"(wB[c]));

    // Stage h0 (swizzled).
    if (tid < 128) {
        int q = tid >> 5, u = (tid >> 2) & 7, e = tid & 3;
        h_s[0][q * 32 + ((u + q) & 7) * 4 + e] = h0[b * 128 + tid];
    }

    // Writer-side swizzled indices (computed once).
    const int wiA = w * 32 + (((oo >> 2) + w) & 7) * 4 + (oo & 3);
    const int wiB = w * 32 + ((4 + (oo >> 2) + w) & 7) * 4 + (oo & 3);

    // x_proj register rings: 8 steps ahead, for both outputs.
    const XPT* xpb = xp + (size_t)b * (TT * 128);
    float xvA[8], xvB[8];
#pragma unroll
    for (int s = 0; s < 8; ++s) {
        xvA[s] = (float)xpb[s * 128 + A];
        xvB[s] = (float)xpb[s * 128 + Bo];
    }
    lds_barrier();

    for (int tw = 0; tw < TT; tw += 8) {
#pragma unroll
        for (int ts = 0; ts < 8; ++ts) {
            const int c = ts & 1;    // static double-buffer index
            // 8 conflict-free b128 reads: this lane's K-quarter (32 f32).
            const float* hq = &h_s[c][kq * 32];
            f32x4 h4[8];
#pragma unroll
            for (int uu = 0; uu < 8; ++uu) h4[uu] = *(const f32x4*)&hq[uu * 4];

            f32x4 sA = f32x4{0.f, 0.f, 0.f, 0.f};
            f32x4 sB = f32x4{0.f, 0.f, 0.f, 0.f};
#pragma unroll
            for (int uu = 0; uu < 8; ++uu) {
                sA += wA[uu] * h4[uu];
                sB += wB[uu] * h4[uu];
            }
            float pA = (sA[0] + sA[1]) + (sA[2] + sA[3]);
            float pB = (sB[0] + sB[1]) + (sB[2] + sB[3]);
            // Reduce over the 4 K-quarters entirely on the VALU pipe.
            pA = xor16_sum(pA);  pB = xor16_sum(pB);
            pA = xor32_sum(pA);  pB = xor32_sum(pB);

            float hA = fast_tanh(pA + xvA[ts]);
            float hB = fast_tanh(pB + xvB[ts]);
            if (kq == 0) {
                h_s[c ^ 1][wiA] = hA;
                h_s[c ^ 1][wiB] = hB;
            }
            // refill ring slots for step tw+8+ts; loads stay in flight
            // across the raw barriers (no vmcnt drain).
            if (tw + 8 < TT) {
                xvA[ts] = (float)xpb[(size_t)(tw + 8 + ts) * 128 + A];
                xvB[ts] = (float)xpb[(size_t)(tw + 8 + ts) * 128 + Bo];
            }
            lds_barrier();
        }
    }
    if (tid < 128) {
        int q = tid >> 5, u = (tid >> 2) & 7, e = tid & 3;
        hlast[b * 128 + tid] = h_s[0][q * 32 + ((u + q) & 7) * 4 + e];
    }
}

// ---------------------------------------------------------------------------
// Kernel 3: MLP head. hidden = relu(h @ W1^T + b1) [256]; logits = hidden @ W2^T + b2 [4]
// One block per batch row. Also writes last_hidden to d_out. (unchanged)
// ---------------------------------------------------------------------------
__global__ __launch_bounds__(256, 2) void mlp_head(
    const float* __restrict__ hlast, const float* __restrict__ W1,
    const float* __restrict__ b1, const float* __restrict__ W2,
    const float* __restrict__ b2, float* __restrict__ out)
{
    const int b = blockIdx.x, tid = threadIdx.x;
    __shared__ float h_row[128];
    __shared__ float hid[256];

    if (tid < 128) {
        float hv = hlast[b * 128 + tid];
        h_row[tid] = hv;
        out[1024 + b * 128 + tid] = hv;   // last_hidden output (fp32)
    }
    __syncthreads();

    // hidden[tid] = relu(b1[tid] + sum_k W1[tid][k] * h[k]); W1 from L2
    {
        float acc = b1[tid];
        const float4* wrow = (const float4*)(W1 + (size_t)tid * 128);
#pragma unroll
        for (int k4 = 0; k4 < 32; ++k4) {
            float4 wv = wrow[k4];
            acc += wv.x * h_row[k4 * 4 + 0] + wv.y * h_row[k4 * 4 + 1]
                 + wv.z * h_row[k4 * 4 + 2] + wv.w * h_row[k4 * 4 + 3];
        }
        hid[tid] = fmaxf(acc, 0.f);
    }
    __syncthreads();

    // logits: wave w -> class w; 64-lane strided partials + shuffle reduce
    const int wv = tid >> 6, lane = tid & 63;
    float s = 0.f;
#pragma unroll
    for (int qq = 0; qq < 4; ++qq)
        s += hid[qq * 64 + lane] * W2[wv * 256 + qq * 64 + lane];
#pragma unroll
    for (int off = 32; off > 0; off >>= 1) s += __shfl_down(s, off);
    if (lane == 0) out[b * 4 + wv] = s + b2[wv];
}

// ---------------------------------------------------------------------------
extern "C" void kernel_launch(void* const* d_in, const int* in_sizes, int n_in,
                              void* d_out, int out_size, void* d_ws, size_t ws_size,
                              hipStream_t stream)
{
    const int*   x   = (const int*)d_in[0];
    const float* h0  = (const float*)d_in[1];
    const float* emb = (const float*)d_in[2];
    const float* Wih = (const float*)d_in[3];
    const float* Whh = (const float*)d_in[4];
    const float* bih = (const float*)d_in[5];
    const float* bhh = (const float*)d_in[6];
    const float* W1  = (const float*)d_in[7];
    const float* b1  = (const float*)d_in[8];
    const float* W2  = (const float*)d_in[9];
    const float* b2  = (const float*)d_in[10];
    float* out = (float*)d_out;

    const size_t xp_f32_bytes = (size_t)MM * 128 * sizeof(float);   // 64 MB
    const size_t hl_bytes     = (size_t)BB * 128 * sizeof(float);   // 128 KB

    if (ws_size >= xp_f32_bytes + hl_bytes) {
        float* xpw = (float*)d_ws;
        float* hl  = (float*)((char*)d_ws + xp_f32_bytes);
        embed_gemm<float><<<MM / 128, 256, 0, stream>>>(x, emb, Wih, bih, bhh, xpw);
        rnn_scan<float><<<BB, 256, 0, stream>>>(xpw, Whh, h0, hl);
        mlp_head<<<BB, 256, 0, stream>>>(hl, W1, b1, W2, b2, out);
    } else {
        // Fallback: bf16 x_proj storage (32 MB) if workspace is small
        __bf16* xpw = (__bf16*)d_ws;
        float*  hl  = (float*)((char*)d_ws + (size_t)MM * 128 * sizeof(__bf16));
        embed_gemm<__bf16><<<MM / 128, 256, 0, stream>>>(x, emb, Wih, bih, bhh, xpw);
        rnn_scan<__bf16><<<BB, 256, 0, stream>>>(xpw, Whh, h0, hl);
        mlp_head<<<BB, 256, 0, stream>>>(hl, W1, b1, W2, b2, out);
    }
}